// Round 8
// baseline (749.183 us; speedup 1.0000x reference)
//
#include <hip/hip_runtime.h>
#include <math.h>

#define NN 50000
#define NE 500000
#define HIDS 128
#define MCOLS 896   // q(256) k(256) v(256) skip(128)
#define NLAYERS 3

typedef __attribute__((ext_vector_type(8))) short short8;
typedef __attribute__((ext_vector_type(4))) float floatx4;
typedef _Float16 half8v __attribute__((ext_vector_type(8)));

// ---------- helpers ----------
static __device__ __forceinline__ unsigned short f2bf(float f) {
    unsigned u = __float_as_uint(f);
    u += 0x7fffu + ((u >> 16) & 1u);   // RNE
    return (unsigned short)(u >> 16);
}
static __device__ __forceinline__ unsigned short f2h(float f) {
    union { _Float16 h; unsigned short u; } c;
    c.h = (_Float16)f;
    return c.u;
}
// VALU-rate width-16 sum via DPP: xor1, xor2 (quad_perm), ror4, ror8 (row rotate).
#define DPP_ADD(v, ctrl) \
    v += __int_as_float(__builtin_amdgcn_mov_dpp(__float_as_int(v), ctrl, 0xf, 0xf, true))
static __device__ __forceinline__ float wred16(float v) {
    DPP_ADD(v, 0xB1);    // quad_perm [1,0,3,2]  : lane ^ 1
    DPP_ADD(v, 0x4E);    // quad_perm [2,3,0,1]  : lane ^ 2
    DPP_ADD(v, 0x124);   // row_ror:4            : quad rotate
    DPP_ADD(v, 0x128);   // row_ror:8            : half-row rotate
    return v;
}
static __device__ __forceinline__ float wred64(float v) {
    v += __shfl_xor(v, 1, 64);
    v += __shfl_xor(v, 2, 64);
    v += __shfl_xor(v, 4, 64);
    v += __shfl_xor(v, 8, 64);
    v += __shfl_xor(v, 16, 64);
    v += __shfl_xor(v, 32, 64);
    return v;
}

// ---------- CSR build ----------
__global__ __launch_bounds__(256) void eatb_count(const int* __restrict__ tgt, int* __restrict__ cnt) {
    int e = blockIdx.x * 256 + threadIdx.x;
    if (e < NE) atomicAdd(&cnt[tgt[e]], 1);
}

__global__ __launch_bounds__(256) void eatb_blocksum(const int* __restrict__ cnt, int* __restrict__ bsums) {
    __shared__ int sm[256];
    int i = blockIdx.x * 256 + threadIdx.x;
    sm[threadIdx.x] = (i < NN) ? cnt[i] : 0;
    __syncthreads();
    for (int off = 128; off > 0; off >>= 1) {
        if (threadIdx.x < off) sm[threadIdx.x] += sm[threadIdx.x + off];
        __syncthreads();
    }
    if (threadIdx.x == 0) bsums[blockIdx.x] = sm[0];
}

__global__ __launch_bounds__(256) void eatb_scanb(int* __restrict__ bsums, int nb) {
    __shared__ int sm[256];
    int t = threadIdx.x;
    int v = (t < nb) ? bsums[t] : 0;
    sm[t] = v;
    __syncthreads();
    for (int off = 1; off < 256; off <<= 1) {
        int x = (t >= off) ? sm[t - off] : 0;
        __syncthreads();
        sm[t] += x;
        __syncthreads();
    }
    if (t < nb) bsums[t] = sm[t] - v;   // exclusive
}

__global__ __launch_bounds__(256) void eatb_rowstart(const int* __restrict__ cnt, const int* __restrict__ bsums,
                                                     int* __restrict__ row_start) {
    __shared__ int sm[256];
    int t = threadIdx.x;
    int i = blockIdx.x * 256 + t;
    int v = (i < NN) ? cnt[i] : 0;
    sm[t] = v;
    __syncthreads();
    for (int off = 1; off < 256; off <<= 1) {
        int x = (t >= off) ? sm[t - off] : 0;
        __syncthreads();
        sm[t] += x;
        __syncthreads();
    }
    int excl = sm[t] - v + bsums[blockIdx.x];
    if (i < NN) row_start[i] = excl;
    if (i == NN - 1) row_start[NN] = excl + v;
}

__global__ __launch_bounds__(256) void eatb_scatter(const int* __restrict__ src, const int* __restrict__ tgt,
                                                    const float* __restrict__ ea, const int* __restrict__ row_start,
                                                    int* __restrict__ cursor, int2* __restrict__ csr) {
    int e = blockIdx.x * 256 + threadIdx.x;
    if (e >= NE) return;
    int t = tgt[e];
    int pos = atomicAdd(&cursor[t], 1);
    int2 val;
    val.x = src[e];
    val.y = __float_as_int(ea[e]);
    csr[row_start[t] + pos] = val;
}

// ---------- pack transposed bf16 weights: WcatT[l][c=0..895][k=0..127] ----------
__global__ __launch_bounds__(256) void eatb_packw(const float* __restrict__ Wq, const float* __restrict__ Wk,
                                                  const float* __restrict__ Wv, const float* __restrict__ Ws,
                                                  const float* __restrict__ bq, const float* __restrict__ bk,
                                                  const float* __restrict__ bv, const float* __restrict__ bs,
                                                  unsigned short* __restrict__ Wt, float* __restrict__ bcat) {
    int idx = blockIdx.x * 256 + threadIdx.x;
    const int WTOT = NLAYERS * MCOLS * HIDS;
    if (idx < WTOT) {
        int l = idx / (MCOLS * HIDS);
        int rem = idx % (MCOLS * HIDS);
        int c = rem / HIDS, k = rem % HIDS;
        float v;
        if (c < 256)      v = Wq[(l * HIDS + k) * 256 + c];
        else if (c < 512) v = Wk[(l * HIDS + k) * 256 + c - 256];
        else if (c < 768) v = Wv[(l * HIDS + k) * 256 + c - 512];
        else              v = Ws[(l * HIDS + k) * 128 + c - 768];
        Wt[idx] = f2bf(v);
    } else {
        int i2 = idx - WTOT;
        if (i2 < NLAYERS * MCOLS) {
            int l = i2 / MCOLS, c = i2 % MCOLS;
            float v;
            if (c < 256)      v = bq[l * 256 + c];
            else if (c < 512) v = bk[l * 256 + c - 256];
            else if (c < 768) v = bv[l * 256 + c - 512];
            else              v = bs[l * 128 + c - 768];
            bcat[i2] = v;
        }
    }
}

// ---------- input layernorm (wave per node) -> fp32 xcur + bf16 xb ----------
__global__ __launch_bounds__(256) void eatb_ln_in(const float* __restrict__ x, const float* __restrict__ g,
                                                  const float* __restrict__ b, float* __restrict__ xout,
                                                  unsigned short* __restrict__ xb) {
    int wid = threadIdx.x >> 6, lane = threadIdx.x & 63;
    int n = blockIdx.x * 4 + wid;
    if (n >= NN) return;
    float2 v = *(const float2*)(x + (size_t)n * HIDS + 2 * lane);
    float mu = wred64(v.x + v.y) * (1.f / 128.f);
    float cx = v.x - mu, cy = v.y - mu;
    float var = wred64(cx * cx + cy * cy) * (1.f / 128.f);
    float r = rsqrtf(var + 1e-5f);
    float2 g2 = *(const float2*)(g + 2 * lane);
    float2 b2 = *(const float2*)(b + 2 * lane);
    float2 o;
    o.x = cx * r * g2.x + b2.x;
    o.y = cy * r * g2.y + b2.y;
    *(float2*)(xout + (size_t)n * HIDS + 2 * lane) = o;
    unsigned pk = (unsigned)f2bf(o.x) | ((unsigned)f2bf(o.y) << 16);
    *(unsigned*)(xb + (size_t)n * HIDS + 2 * lane) = pk;
}

// ---------- bf16 MFMA GEMM, zero staging: A frags in registers, B via L1/L2 ----------
// grid 782; block 256 (4 waves); wave w -> rows r0+w*16..+15; loop 14 col-tiles of 64.
// LDS = C transpose only (64x68 f32, 17408 B -> up to 8 blocks/CU).
// qpack f16 [NN][256]; kvpack f16 [NN][kh0|kh1|vh0|vh1] (plain, contiguous);
// skipbuf f16 [NN][128]. All routed stores fully coalesced (8B/thread contiguous).
__global__ __launch_bounds__(256, 4) void eatb_gemm(const unsigned short* __restrict__ xb,
                                                    const unsigned short* __restrict__ Wt,
                                                    const float* __restrict__ bias,
                                                    unsigned short* __restrict__ qpack,
                                                    unsigned short* __restrict__ kvpack,
                                                    unsigned short* __restrict__ skipbuf) {
    __shared__ __align__(16) float Cs[64 * 68];

    int tid = threadIdx.x;
    int r0 = blockIdx.x * 64;
    int wid = tid >> 6, lane = tid & 63;
    int fr = lane & 15;
    int kq = (lane >> 4) * 8;

    // A fragments: row r0+wid*16+fr, k = ks*32+kq..+7 — loop-invariant, 16 VGPRs total
    int ar = r0 + wid * 16 + fr;
    bool aok = ar < NN;
    const unsigned short* aptr = xb + (size_t)(aok ? ar : 0) * HIDS;
    short8 afk[4];
    #pragma unroll
    for (int ks = 0; ks < 4; ++ks) afk[ks] = *(const short8*)(aptr + ks * 32 + kq);
    if (!aok) {
        short8 z = {};
        afk[0] = z; afk[1] = z; afk[2] = z; afk[3] = z;
    }

    int cl = (tid & 15) * 4;
    for (int ci = 0; ci < 14; ++ci) {
        int c0 = ci * 64;
        floatx4 acc[4] = {};
        #pragma unroll
        for (int n = 0; n < 4; ++n) {
            const unsigned short* bptr = Wt + (size_t)(c0 + n * 16 + fr) * HIDS;
            #pragma unroll
            for (int ks = 0; ks < 4; ++ks) {
                short8 bf = *(const short8*)(bptr + ks * 32 + kq);
                acc[n] = __builtin_amdgcn_mfma_f32_16x16x32_bf16(afk[ks], bf, acc[n], 0, 0, 0);
            }
        }
        // C fragments -> LDS (row = wid*16 + (lane>>4)*4+rg, col = n*16+fr)
        #pragma unroll
        for (int n = 0; n < 4; ++n)
            #pragma unroll
            for (int rg = 0; rg < 4; ++rg)
                Cs[(wid * 16 + (lane >> 4) * 4 + rg) * 68 + n * 16 + fr] = acc[n][rg];
        __syncthreads();

        // epilogue: thread t -> cols c0+4*(t&15).., rows (t>>4)+16p ; contiguous 8B stores
        int C = c0 + cl;
        float4 b4 = *(const float4*)(bias + C);
        #pragma unroll
        for (int p = 0; p < 4; ++p) {
            int rr = (tid >> 4) + 16 * p;
            int gr = r0 + rr;
            if (gr < NN) {
                float4 cv = *(const float4*)(Cs + rr * 68 + cl);
                ushort4 o;
                o.x = f2h(cv.x + b4.x);
                o.y = f2h(cv.y + b4.y);
                o.z = f2h(cv.z + b4.z);
                o.w = f2h(cv.w + b4.w);
                if (C < 256)      *(ushort4*)(qpack + (size_t)gr * 256 + C) = o;
                else if (C < 768) *(ushort4*)(kvpack + (size_t)gr * 512 + (C - 256)) = o;
                else              *(ushort4*)(skipbuf + (size_t)gr * 128 + (C - 768)) = o;
            }
        }
        __syncthreads();
    }
}

// ---------- fused attention + epilogue: one wave per target node ----------
// lane map: slot = lane>>5 (edge slot), h = (lane>>4)&1, sl = lane&15 (dims sl*8..sl*8+7)
// kvpack plain [kh0|kh1|vh0|vh1]: k at s*512 + h*128 + sl*8, v at +256 (full-line reads).
// f16 tables; q pre-scaled by 1/sqrt(128). No-max softmax (|alpha| << 88).
__global__ __launch_bounds__(256) void eatb_attn(const unsigned short* __restrict__ qpack,
                                                 const unsigned short* __restrict__ kvpack,
                                                 const unsigned short* __restrict__ skipbuf,
                                                 const int2* __restrict__ csr, const int* __restrict__ row_start,
                                                 const float* __restrict__ Wel, const float* __restrict__ g,
                                                 const float* __restrict__ beta, const float* __restrict__ xcur,
                                                 float* __restrict__ dst, unsigned short* __restrict__ xbout) {
    int wid = threadIdx.x >> 6;
    int lane = threadIdx.x & 63;
    int n = blockIdx.x * 4 + wid;
    if (n >= NN) return;
    int slot = lane >> 5;
    int h = (lane >> 4) & 1;
    int sl = lane & 15;
    int dbase = sl * 8;

    const float rs = 0.08838834764831845f;   // 1/sqrt(128), folded into q
    const _Float16* qh16 = (const _Float16*)qpack;
    const _Float16* kvh = (const _Float16*)kvpack;

    half8v qh = *(const half8v*)(qh16 + n * 256 + h * 128 + dbase);
    float q0 = (float)qh[0] * rs, q1 = (float)qh[1] * rs, q2 = (float)qh[2] * rs, q3 = (float)qh[3] * rs;
    float q4 = (float)qh[4] * rs, q5 = (float)qh[5] * rs, q6 = (float)qh[6] * rs, q7 = (float)qh[7] * rs;
    const float* wep = Wel + h * 128 + dbase;
    float4 wea = *(const float4*)wep;
    float4 web = *(const float4*)(wep + 4);
    float qwe = wred16(q0 * wea.x + q1 * wea.y + q2 * wea.z + q3 * wea.w +
                       q4 * web.x + q5 * web.y + q6 * web.z + q7 * web.w);

    float sA = 0.f, seaA = 0.f, sB = 0.f, seaB = 0.f;
    float aA0 = 0.f, aA1 = 0.f, aA2 = 0.f, aA3 = 0.f, aA4 = 0.f, aA5 = 0.f, aA6 = 0.f, aA7 = 0.f;
    float aB0 = 0.f, aB1 = 0.f, aB2 = 0.f, aB3 = 0.f, aB4 = 0.f, aB5 = 0.f, aB6 = 0.f, aB7 = 0.f;
    int beg = row_start[n], end = row_start[n + 1];
    int nit = (end - beg + 3) >> 2;
    int lbase = (h << 7) + (sl << 3);        // 32-bit offsets -> saddr-form loads
    for (int it = 0; it < nit; ++it) {
        int eA = beg + 4 * it + slot;
        int eB = eA + 2;
        bool vA = eA < end, vB = eB < end;
        int2 seA = csr[vA ? eA : beg];
        int2 seB = csr[vB ? eB : beg];
        int koA = (seA.x << 9) + lbase;
        int koB = (seB.x << 9) + lbase;
        half8v kqA = *(const half8v*)(kvh + koA);
        half8v vqA = *(const half8v*)(kvh + koA + 256);
        half8v kqB = *(const half8v*)(kvh + koB);
        half8v vqB = *(const half8v*)(kvh + koB + 256);
        float eaA = __int_as_float(seA.y);
        float eaB = __int_as_float(seB.y);
        float pA = q0 * (float)kqA[0] + q1 * (float)kqA[1] + q2 * (float)kqA[2] + q3 * (float)kqA[3] +
                   q4 * (float)kqA[4] + q5 * (float)kqA[5] + q6 * (float)kqA[6] + q7 * (float)kqA[7];
        float pB = q0 * (float)kqB[0] + q1 * (float)kqB[1] + q2 * (float)kqB[2] + q3 * (float)kqB[3] +
                   q4 * (float)kqB[4] + q5 * (float)kqB[5] + q6 * (float)kqB[6] + q7 * (float)kqB[7];
        pA = wred16(pA);
        pB = wred16(pB);
        float wA = vA ? __expf(pA + eaA * qwe) : 0.f;
        float wB = vB ? __expf(pB + eaB * qwe) : 0.f;
        sA += wA;
        sB += wB;
        seaA = fmaf(wA, eaA, seaA);
        seaB = fmaf(wB, eaB, seaB);
        aA0 = fmaf(wA, (float)vqA[0], aA0);  aB0 = fmaf(wB, (float)vqB[0], aB0);
        aA1 = fmaf(wA, (float)vqA[1], aA1);  aB1 = fmaf(wB, (float)vqB[1], aB1);
        aA2 = fmaf(wA, (float)vqA[2], aA2);  aB2 = fmaf(wB, (float)vqB[2], aB2);
        aA3 = fmaf(wA, (float)vqA[3], aA3);  aB3 = fmaf(wB, (float)vqB[3], aB3);
        aA4 = fmaf(wA, (float)vqA[4], aA4);  aB4 = fmaf(wB, (float)vqB[4], aB4);
        aA5 = fmaf(wA, (float)vqA[5], aA5);  aB5 = fmaf(wB, (float)vqB[5], aB5);
        aA6 = fmaf(wA, (float)vqA[6], aA6);  aB6 = fmaf(wB, (float)vqB[6], aB6);
        aA7 = fmaf(wA, (float)vqA[7], aA7);  aB7 = fmaf(wB, (float)vqB[7], aB7);
    }
    float s = sA + sB, sea = seaA + seaB;
    float a0 = aA0 + aB0, a1 = aA1 + aB1, a2 = aA2 + aB2, a3 = aA3 + aB3;
    float a4 = aA4 + aB4, a5 = aA5 + aB5, a6 = aA6 + aB6, a7 = aA7 + aB7;

    // merge the two edge slots (lane ^ 32): plain sums
    s += __shfl_xor(s, 32, 64);
    sea += __shfl_xor(sea, 32, 64);
    a0 += __shfl_xor(a0, 32, 64);
    a1 += __shfl_xor(a1, 32, 64);
    a2 += __shfl_xor(a2, 32, 64);
    a3 += __shfl_xor(a3, 32, 64);
    a4 += __shfl_xor(a4, 32, 64);
    a5 += __shfl_xor(a5, 32, 64);
    a6 += __shfl_xor(a6, 32, 64);
    a7 += __shfl_xor(a7, 32, 64);

    float inv = (s > 0.f) ? 1.f / s : 1.f;
    float sw = sea * inv;
    float o0 = a0 * inv + sw * wea.x;
    float o1 = a1 * inv + sw * wea.y;
    float o2 = a2 * inv + sw * wea.z;
    float o3 = a3 * inv + sw * wea.w;
    float o4 = a4 * inv + sw * web.x;
    float o5 = a5 * inv + sw * web.y;
    float o6 = a6 * inv + sw * web.z;
    float o7 = a7 * inv + sw * web.w;
    // head mean (h <-> h^1 is lane ^ 16)
    o0 = 0.5f * (o0 + __shfl_xor(o0, 16, 64));
    o1 = 0.5f * (o1 + __shfl_xor(o1, 16, 64));
    o2 = 0.5f * (o2 + __shfl_xor(o2, 16, 64));
    o3 = 0.5f * (o3 + __shfl_xor(o3, 16, 64));
    o4 = 0.5f * (o4 + __shfl_xor(o4, 16, 64));
    o5 = 0.5f * (o5 + __shfl_xor(o5, 16, 64));
    o6 = 0.5f * (o6 + __shfl_xor(o6, 16, 64));
    o7 = 0.5f * (o7 + __shfl_xor(o7, 16, 64));

    // + skip (f16), ELU, residual, LN (dims dbase..dbase+7; 4x redundant across (slot,h))
    const _Float16* skp = (const _Float16*)skipbuf + n * 128 + dbase;
    half8v skh = *(const half8v*)skp;
    const float* xrp = xcur + n * 128 + dbase;
    float4 xra = *(const float4*)xrp, xrb = *(const float4*)(xrp + 4);
    float y0 = o0 + (float)skh[0], y1 = o1 + (float)skh[1], y2 = o2 + (float)skh[2], y3 = o3 + (float)skh[3];
    float y4 = o4 + (float)skh[4], y5 = o5 + (float)skh[5], y6 = o6 + (float)skh[6], y7 = o7 + (float)skh[7];
    y0 = (y0 > 0.f) ? y0 : __expf(y0) - 1.f;
    y1 = (y1 > 0.f) ? y1 : __expf(y1) - 1.f;
    y2 = (y2 > 0.f) ? y2 : __expf(y2) - 1.f;
    y3 = (y3 > 0.f) ? y3 : __expf(y3) - 1.f;
    y4 = (y4 > 0.f) ? y4 : __expf(y4) - 1.f;
    y5 = (y5 > 0.f) ? y5 : __expf(y5) - 1.f;
    y6 = (y6 > 0.f) ? y6 : __expf(y6) - 1.f;
    y7 = (y7 > 0.f) ? y7 : __expf(y7) - 1.f;
    float p0 = xra.x + y0, p1 = xra.y + y1, p2 = xra.z + y2, p3 = xra.w + y3;
    float p4 = xrb.x + y4, p5 = xrb.y + y5, p6 = xrb.z + y6, p7 = xrb.w + y7;
    float mu = wred16(p0 + p1 + p2 + p3 + p4 + p5 + p6 + p7) * (1.f / 128.f);
    float c0 = p0 - mu, c1 = p1 - mu, c2 = p2 - mu, c3 = p3 - mu;
    float c4 = p4 - mu, c5 = p5 - mu, c6 = p6 - mu, c7 = p7 - mu;
    float var = wred16(c0 * c0 + c1 * c1 + c2 * c2 + c3 * c3 +
                       c4 * c4 + c5 * c5 + c6 * c6 + c7 * c7) * (1.f / 128.f);
    float r = rsqrtf(var + 1e-5f);
    if (lane < 16) {
        const float* gp = g + dbase;
        const float* bp = beta + dbase;
        float4 ga = *(const float4*)gp, gb = *(const float4*)(gp + 4);
        float4 ba = *(const float4*)bp, bb = *(const float4*)(bp + 4);
        float4 oa, ob;
        oa.x = c0 * r * ga.x + ba.x; oa.y = c1 * r * ga.y + ba.y;
        oa.z = c2 * r * ga.z + ba.z; oa.w = c3 * r * ga.w + ba.w;
        ob.x = c4 * r * gb.x + bb.x; ob.y = c5 * r * gb.y + bb.y;
        ob.z = c6 * r * gb.z + bb.z; ob.w = c7 * r * gb.w + bb.w;
        float* dp = dst + n * 128 + dbase;
        *(float4*)dp = oa;
        *(float4*)(dp + 4) = ob;
        if (xbout) {
            uint4 pk;
            pk.x = (unsigned)f2bf(oa.x) | ((unsigned)f2bf(oa.y) << 16);
            pk.y = (unsigned)f2bf(oa.z) | ((unsigned)f2bf(oa.w) << 16);
            pk.z = (unsigned)f2bf(ob.x) | ((unsigned)f2bf(ob.y) << 16);
            pk.w = (unsigned)f2bf(ob.z) | ((unsigned)f2bf(ob.w) << 16);
            *(uint4*)(xbout + n * 128 + dbase) = pk;
        }
    }
}

// ---------- launch ----------
extern "C" void kernel_launch(void* const* d_in, const int* in_sizes, int n_in,
                              void* d_out, int out_size, void* d_ws, size_t ws_size,
                              hipStream_t stream) {
    const float* x       = (const float*)d_in[0];
    const int*   ei      = (const int*)d_in[1];
    const float* eattr   = (const float*)d_in[2];
    const float* ln_in_g = (const float*)d_in[3];
    const float* ln_in_b = (const float*)d_in[4];
    const float* Wq = (const float*)d_in[5];
    const float* bq = (const float*)d_in[6];
    const float* Wk = (const float*)d_in[7];
    const float* bk = (const float*)d_in[8];
    const float* Wv = (const float*)d_in[9];
    const float* bv = (const float*)d_in[10];
    const float* We = (const float*)d_in[11];
    const float* Ws = (const float*)d_in[12];
    const float* bs = (const float*)d_in[13];
    const float* ln_g = (const float*)d_in[14];
    const float* ln_b = (const float*)d_in[15];
    float* out = (float*)d_out;

    char* p = (char*)d_ws;
    auto carve = [&](size_t bytes) {
        char* r = p;
        p += (bytes + 255) & ~(size_t)255;
        return (void*)r;
    };
    int*  cursor    = (int*)carve((size_t)NN * 4);
    int*  row_start = (int*)carve((size_t)(NN + 1) * 4);
    int*  bsums     = (int*)carve(1024);
    int2* csr       = (int2*)carve((size_t)NE * 8);
    unsigned short* WcatT = (unsigned short*)carve((size_t)NLAYERS * MCOLS * HIDS * 2);
    float* bcat     = (float*)carve((size_t)NLAYERS * MCOLS * 4);
    float* xcur     = (float*)carve((size_t)NN * HIDS * 4);
    unsigned short* qpack  = (unsigned short*)carve((size_t)NN * 256 * 2);
    unsigned short* kvpack = (unsigned short*)carve((size_t)NN * 512 * 2);
    unsigned short* skipbuf = (unsigned short*)carve((size_t)NN * HIDS * 2);
    unsigned short* xb = (unsigned short*)carve((size_t)NN * HIDS * 2);

    const int NB_N = (NN + 255) / 256;       // 196
    const int NB_E = (NE + 255) / 256;       // 1954
    const int NODE_BLOCKS = (NN + 3) / 4;    // 12500

    // CSR build (edge_index layout: src = ei[0:E], tgt = ei[E:2E])
    hipMemsetAsync(cursor, 0, (size_t)NN * 4, stream);
    eatb_count<<<NB_E, 256, 0, stream>>>(ei + NE, cursor);
    eatb_blocksum<<<NB_N, 256, 0, stream>>>(cursor, bsums);
    eatb_scanb<<<1, 256, 0, stream>>>(bsums, NB_N);
    eatb_rowstart<<<NB_N, 256, 0, stream>>>(cursor, bsums, row_start);
    hipMemsetAsync(cursor, 0, (size_t)NN * 4, stream);
    eatb_scatter<<<NB_E, 256, 0, stream>>>(ei, ei + NE, eattr, row_start, cursor, csr);

    // pack weights (transposed bf16) + biases
    {
        int tot = NLAYERS * MCOLS * HIDS + NLAYERS * MCOLS;
        eatb_packw<<<(tot + 255) / 256, 256, 0, stream>>>(Wq, Wk, Wv, Ws, bq, bk, bv, bs, WcatT, bcat);
    }

    // input layernorm -> xcur (fp32) + xb (bf16)
    eatb_ln_in<<<NODE_BLOCKS, 256, 0, stream>>>(x, ln_in_g, ln_in_b, xcur, xb);

    // layers
    const int GEMM_BLOCKS = (NN + 63) / 64;   // 782
    for (int l = 0; l < NLAYERS; ++l) {
        eatb_gemm<<<GEMM_BLOCKS, 256, 0, stream>>>(xb, WcatT + (size_t)l * MCOLS * HIDS,
                                                   bcat + (size_t)l * MCOLS, qpack, kvpack, skipbuf);
        float* dst = (l == NLAYERS - 1) ? out : xcur;
        unsigned short* xbo = (l == NLAYERS - 1) ? nullptr : xb;
        eatb_attn<<<NODE_BLOCKS, 256, 0, stream>>>(qpack, kvpack, skipbuf, csr, row_start,
                                                   We + (size_t)l * 256, ln_g + (size_t)l * 128,
                                                   ln_b + (size_t)l * 128, xcur, dst, xbo);
    }
    (void)in_sizes; (void)n_in; (void)out_size; (void)ws_size;
}

// Round 9
// 525.898 us; speedup vs baseline: 1.4246x; 1.4246x over previous
//
#include <hip/hip_runtime.h>
#include <math.h>

#define NN 50000
#define NE 500000
#define HIDS 128
#define MCOLS 896   // q(256) k(256) v(256) skip(128)
#define NLAYERS 3

typedef __attribute__((ext_vector_type(8))) short short8;
typedef __attribute__((ext_vector_type(4))) float floatx4;
typedef _Float16 half8v __attribute__((ext_vector_type(8)));

#define BSTR 152    // B-tile LDS row stride in shorts (proven conflict-benign in R2-R6)

// ---------- helpers ----------
static __device__ __forceinline__ unsigned short f2bf(float f) {
    unsigned u = __float_as_uint(f);
    u += 0x7fffu + ((u >> 16) & 1u);   // RNE
    return (unsigned short)(u >> 16);
}
static __device__ __forceinline__ unsigned short f2h(float f) {
    union { _Float16 h; unsigned short u; } c;
    c.h = (_Float16)f;
    return c.u;
}
// VALU-rate width-16 sum via DPP: xor1, xor2 (quad_perm), ror4, ror8 (row rotate).
#define DPP_ADD(v, ctrl) \
    v += __int_as_float(__builtin_amdgcn_mov_dpp(__float_as_int(v), ctrl, 0xf, 0xf, true))
static __device__ __forceinline__ float wred16(float v) {
    DPP_ADD(v, 0xB1);    // quad_perm [1,0,3,2]  : lane ^ 1
    DPP_ADD(v, 0x4E);    // quad_perm [2,3,0,1]  : lane ^ 2
    DPP_ADD(v, 0x124);   // row_ror:4            : quad rotate
    DPP_ADD(v, 0x128);   // row_ror:8            : half-row rotate
    return v;
}
static __device__ __forceinline__ float wred64(float v) {
    v += __shfl_xor(v, 1, 64);
    v += __shfl_xor(v, 2, 64);
    v += __shfl_xor(v, 4, 64);
    v += __shfl_xor(v, 8, 64);
    v += __shfl_xor(v, 16, 64);
    v += __shfl_xor(v, 32, 64);
    return v;
}

// ---------- CSR build ----------
__global__ __launch_bounds__(1024) void eatb_count(const int* __restrict__ tgt, int* __restrict__ cnt) {
    int e = blockIdx.x * 1024 + threadIdx.x;
    if (e < NE) atomicAdd(&cnt[tgt[e]], 1);
}

__global__ __launch_bounds__(256) void eatb_blocksum(const int* __restrict__ cnt, int* __restrict__ bsums) {
    __shared__ int sm[256];
    int i = blockIdx.x * 256 + threadIdx.x;
    sm[threadIdx.x] = (i < NN) ? cnt[i] : 0;
    __syncthreads();
    for (int off = 128; off > 0; off >>= 1) {
        if (threadIdx.x < off) sm[threadIdx.x] += sm[threadIdx.x + off];
        __syncthreads();
    }
    if (threadIdx.x == 0) bsums[blockIdx.x] = sm[0];
}

__global__ __launch_bounds__(256) void eatb_scanb(int* __restrict__ bsums, int nb) {
    __shared__ int sm[256];
    int t = threadIdx.x;
    int v = (t < nb) ? bsums[t] : 0;
    sm[t] = v;
    __syncthreads();
    for (int off = 1; off < 256; off <<= 1) {
        int x = (t >= off) ? sm[t - off] : 0;
        __syncthreads();
        sm[t] += x;
        __syncthreads();
    }
    if (t < nb) bsums[t] = sm[t] - v;   // exclusive
}

__global__ __launch_bounds__(256) void eatb_rowstart(const int* __restrict__ cnt, const int* __restrict__ bsums,
                                                     int* __restrict__ row_start) {
    __shared__ int sm[256];
    int t = threadIdx.x;
    int i = blockIdx.x * 256 + t;
    int v = (i < NN) ? cnt[i] : 0;
    sm[t] = v;
    __syncthreads();
    for (int off = 1; off < 256; off <<= 1) {
        int x = (t >= off) ? sm[t - off] : 0;
        __syncthreads();
        sm[t] += x;
        __syncthreads();
    }
    int excl = sm[t] - v + bsums[blockIdx.x];
    if (i < NN) row_start[i] = excl;
}

// scatter atomicAdds on row_start itself: afterwards row_start[n] == END of row n
// (attn derives beg = n ? row_start[n-1] : 0). Saves a memset + cursor array.
__global__ __launch_bounds__(1024) void eatb_scatter(const int* __restrict__ src, const int* __restrict__ tgt,
                                                     const float* __restrict__ ea, int* __restrict__ row_state,
                                                     int2* __restrict__ csr) {
    int e = blockIdx.x * 1024 + threadIdx.x;
    if (e >= NE) return;
    int t = tgt[e];
    int pos = atomicAdd(&row_state[t], 1);
    int2 val;
    val.x = src[e];
    val.y = __float_as_int(ea[e]);
    csr[pos] = val;
}

// ---------- pack transposed bf16 weights: WcatT[l][c=0..895][k=0..127] ----------
__global__ __launch_bounds__(256) void eatb_packw(const float* __restrict__ Wq, const float* __restrict__ Wk,
                                                  const float* __restrict__ Wv, const float* __restrict__ Ws,
                                                  const float* __restrict__ bq, const float* __restrict__ bk,
                                                  const float* __restrict__ bv, const float* __restrict__ bs,
                                                  unsigned short* __restrict__ Wt, float* __restrict__ bcat) {
    int idx = blockIdx.x * 256 + threadIdx.x;
    const int WTOT = NLAYERS * MCOLS * HIDS;
    if (idx < WTOT) {
        int l = idx / (MCOLS * HIDS);
        int rem = idx % (MCOLS * HIDS);
        int c = rem / HIDS, k = rem % HIDS;
        float v;
        if (c < 256)      v = Wq[(l * HIDS + k) * 256 + c];
        else if (c < 512) v = Wk[(l * HIDS + k) * 256 + c - 256];
        else if (c < 768) v = Wv[(l * HIDS + k) * 256 + c - 512];
        else              v = Ws[(l * HIDS + k) * 128 + c - 768];
        Wt[idx] = f2bf(v);
    } else {
        int i2 = idx - WTOT;
        if (i2 < NLAYERS * MCOLS) {
            int l = i2 / MCOLS, c = i2 % MCOLS;
            float v;
            if (c < 256)      v = bq[l * 256 + c];
            else if (c < 512) v = bk[l * 256 + c - 256];
            else if (c < 768) v = bv[l * 256 + c - 512];
            else              v = bs[l * 128 + c - 768];
            bcat[i2] = v;
        }
    }
}

// ---------- input layernorm (wave per node) -> fp32 xcur + bf16 xb ----------
__global__ __launch_bounds__(256) void eatb_ln_in(const float* __restrict__ x, const float* __restrict__ g,
                                                  const float* __restrict__ b, float* __restrict__ xout,
                                                  unsigned short* __restrict__ xb) {
    int wid = threadIdx.x >> 6, lane = threadIdx.x & 63;
    int n = blockIdx.x * 4 + wid;
    if (n >= NN) return;
    float2 v = *(const float2*)(x + (size_t)n * HIDS + 2 * lane);
    float mu = wred64(v.x + v.y) * (1.f / 128.f);
    float cx = v.x - mu, cy = v.y - mu;
    float var = wred64(cx * cx + cy * cy) * (1.f / 128.f);
    float r = rsqrtf(var + 1e-5f);
    float2 g2 = *(const float2*)(g + 2 * lane);
    float2 b2 = *(const float2*)(b + 2 * lane);
    float2 o;
    o.x = cx * r * g2.x + b2.x;
    o.y = cy * r * g2.y + b2.y;
    *(float2*)(xout + (size_t)n * HIDS + 2 * lane) = o;
    unsigned pk = (unsigned)f2bf(o.x) | ((unsigned)f2bf(o.y) << 16);
    *(unsigned*)(xb + (size_t)n * HIDS + 2 * lane) = pk;
}

// ---------- bf16 MFMA GEMM: A in registers (loop-invariant), B via LDS per col-tile ----------
// grid 391; block 512 (8 waves); wave w owns rows r0+w*16..+15; loop 14 col-tiles of 64.
// Traffic: A 25.6 MB (once), B 87.5 MB (L2-hot: W=0.45 MB), stores 87.5 MB.
// LDS: Bs 19456 + Cs 34816 = 54272 B -> 2 blocks/CU (16 waves) for stage/compute overlap.
__global__ __launch_bounds__(512, 4) void eatb_gemm(const unsigned short* __restrict__ xb,
                                                    const unsigned short* __restrict__ Wt,
                                                    const float* __restrict__ bias,
                                                    unsigned short* __restrict__ qpack,
                                                    unsigned short* __restrict__ kvpack,
                                                    unsigned short* __restrict__ skipbuf) {
    __shared__ __align__(16) short Bs[64 * BSTR];   // 19456 B
    __shared__ __align__(16) float Cs[128 * 68];    // 34816 B

    int tid = threadIdx.x;
    int r0 = blockIdx.x * 128;
    int wid = tid >> 6, lane = tid & 63;
    int fr = lane & 15;
    int kq = (lane >> 4) * 8;

    // A fragments: row r0 + wid*16 + fr; loop-invariant across all 14 col-tiles (16 VGPRs)
    int ar = r0 + wid * 16 + fr;
    bool aok = ar < NN;
    const unsigned short* aptr = xb + (size_t)(aok ? ar : 0) * HIDS;
    short8 afk[4];
    #pragma unroll
    for (int ks = 0; ks < 4; ++ks) afk[ks] = *(const short8*)(aptr + ks * 32 + kq);
    if (!aok) {
        short8 z = {};
        afk[0] = z; afk[1] = z; afk[2] = z; afk[3] = z;
    }

    // stage B tile 0: 512 thr x 32 B
    int brow = tid >> 4, bch = (tid & 15) * 8;
    #pragma unroll
    for (int p = 0; p < 2; ++p) {
        int r = brow + p * 32;
        *(uint4*)(Bs + r * BSTR + bch) = *(const uint4*)(Wt + (size_t)r * HIDS + bch);
    }
    __syncthreads();

    int cl = (tid & 15) * 4;
    for (int ci = 0; ci < 14; ++ci) {
        floatx4 acc[4] = {};
        #pragma unroll
        for (int ks = 0; ks < 4; ++ks) {
            int kof = ks * 32 + kq;
            #pragma unroll
            for (int n = 0; n < 4; ++n) {
                short8 bf = *(const short8*)(Bs + (n * 16 + fr) * BSTR + kof);
                acc[n] = __builtin_amdgcn_mfma_f32_16x16x32_bf16(afk[ks], bf, acc[n], 0, 0, 0);
            }
        }
        // C fragments -> LDS
        #pragma unroll
        for (int n = 0; n < 4; ++n)
            #pragma unroll
            for (int rg = 0; rg < 4; ++rg)
                Cs[(wid * 16 + (lane >> 4) * 4 + rg) * 68 + n * 16 + fr] = acc[n][rg];
        __syncthreads();   // all Bs reads + Cs writes complete

        // epilogue (reads Cs) + stage next B (writes Bs) — disjoint LDS, overlap
        int c0 = ci * 64;
        int C = c0 + cl;
        float4 b4 = *(const float4*)(bias + C);
        #pragma unroll
        for (int p = 0; p < 4; ++p) {
            int rr = (tid >> 4) + 32 * p;
            int gr = r0 + rr;
            if (gr < NN) {
                float4 cv = *(const float4*)(Cs + rr * 68 + cl);
                ushort4 o;
                o.x = f2h(cv.x + b4.x);
                o.y = f2h(cv.y + b4.y);
                o.z = f2h(cv.z + b4.z);
                o.w = f2h(cv.w + b4.w);
                if (C < 256)      *(ushort4*)(qpack + (size_t)gr * 256 + C) = o;
                else if (C < 768) *(ushort4*)(kvpack + (size_t)gr * 512 + (C - 256)) = o;
                else              *(ushort4*)(skipbuf + (size_t)gr * 128 + (C - 768)) = o;
            }
        }
        if (ci < 13) {
            #pragma unroll
            for (int p = 0; p < 2; ++p) {
                int r = brow + p * 32;
                *(uint4*)(Bs + r * BSTR + bch) = *(const uint4*)(Wt + (size_t)((ci + 1) * 64 + r) * HIDS + bch);
            }
        }
        __syncthreads();   // Cs free; new Bs visible
    }
}

// ---------- fused attention + epilogue: one wave per target node ----------
// lane map: slot = lane>>5 (edge slot), h = (lane>>4)&1, sl = lane&15 (dims sl*8..sl*8+7)
// kvpack plain [kh0|kh1|vh0|vh1]; f16 tables; q pre-scaled by 1/sqrt(128); no-max softmax.
// row_state[n] = END of row n (beg = row_state[n-1], 0 for n=0).
__global__ __launch_bounds__(256) void eatb_attn(const unsigned short* __restrict__ qpack,
                                                 const unsigned short* __restrict__ kvpack,
                                                 const unsigned short* __restrict__ skipbuf,
                                                 const int2* __restrict__ csr, const int* __restrict__ row_state,
                                                 const float* __restrict__ Wel, const float* __restrict__ g,
                                                 const float* __restrict__ beta, const float* __restrict__ xcur,
                                                 float* __restrict__ dst, unsigned short* __restrict__ xbout) {
    int wid = threadIdx.x >> 6;
    int lane = threadIdx.x & 63;
    int n = blockIdx.x * 4 + wid;
    if (n >= NN) return;
    int slot = lane >> 5;
    int h = (lane >> 4) & 1;
    int sl = lane & 15;
    int dbase = sl * 8;

    const float rs = 0.08838834764831845f;   // 1/sqrt(128), folded into q
    const _Float16* qh16 = (const _Float16*)qpack;
    const _Float16* kvh = (const _Float16*)kvpack;

    half8v qh = *(const half8v*)(qh16 + n * 256 + h * 128 + dbase);
    float q0 = (float)qh[0] * rs, q1 = (float)qh[1] * rs, q2 = (float)qh[2] * rs, q3 = (float)qh[3] * rs;
    float q4 = (float)qh[4] * rs, q5 = (float)qh[5] * rs, q6 = (float)qh[6] * rs, q7 = (float)qh[7] * rs;
    const float* wep = Wel + h * 128 + dbase;
    float4 wea = *(const float4*)wep;
    float4 web = *(const float4*)(wep + 4);
    float qwe = wred16(q0 * wea.x + q1 * wea.y + q2 * wea.z + q3 * wea.w +
                       q4 * web.x + q5 * web.y + q6 * web.z + q7 * web.w);

    float sA = 0.f, seaA = 0.f, sB = 0.f, seaB = 0.f;
    float aA0 = 0.f, aA1 = 0.f, aA2 = 0.f, aA3 = 0.f, aA4 = 0.f, aA5 = 0.f, aA6 = 0.f, aA7 = 0.f;
    float aB0 = 0.f, aB1 = 0.f, aB2 = 0.f, aB3 = 0.f, aB4 = 0.f, aB5 = 0.f, aB6 = 0.f, aB7 = 0.f;
    int end = row_state[n];
    int beg = (n > 0) ? row_state[n - 1] : 0;
    int nit = (end - beg + 3) >> 2;
    int lbase = (h << 7) + (sl << 3);        // 32-bit offsets -> saddr-form loads
    for (int it = 0; it < nit; ++it) {
        int eA = beg + 4 * it + slot;
        int eB = eA + 2;
        bool vA = eA < end, vB = eB < end;
        int2 seA = csr[vA ? eA : beg];
        int2 seB = csr[vB ? eB : beg];
        int koA = (seA.x << 9) + lbase;
        int koB = (seB.x << 9) + lbase;
        half8v kqA = *(const half8v*)(kvh + koA);
        half8v vqA = *(const half8v*)(kvh + koA + 256);
        half8v kqB = *(const half8v*)(kvh + koB);
        half8v vqB = *(const half8v*)(kvh + koB + 256);
        float eaA = __int_as_float(seA.y);
        float eaB = __int_as_float(seB.y);
        float pA = q0 * (float)kqA[0] + q1 * (float)kqA[1] + q2 * (float)kqA[2] + q3 * (float)kqA[3] +
                   q4 * (float)kqA[4] + q5 * (float)kqA[5] + q6 * (float)kqA[6] + q7 * (float)kqA[7];
        float pB = q0 * (float)kqB[0] + q1 * (float)kqB[1] + q2 * (float)kqB[2] + q3 * (float)kqB[3] +
                   q4 * (float)kqB[4] + q5 * (float)kqB[5] + q6 * (float)kqB[6] + q7 * (float)kqB[7];
        pA = wred16(pA);
        pB = wred16(pB);
        float wA = vA ? __expf(pA + eaA * qwe) : 0.f;
        float wB = vB ? __expf(pB + eaB * qwe) : 0.f;
        sA += wA;
        sB += wB;
        seaA = fmaf(wA, eaA, seaA);
        seaB = fmaf(wB, eaB, seaB);
        aA0 = fmaf(wA, (float)vqA[0], aA0);  aB0 = fmaf(wB, (float)vqB[0], aB0);
        aA1 = fmaf(wA, (float)vqA[1], aA1);  aB1 = fmaf(wB, (float)vqB[1], aB1);
        aA2 = fmaf(wA, (float)vqA[2], aA2);  aB2 = fmaf(wB, (float)vqB[2], aB2);
        aA3 = fmaf(wA, (float)vqA[3], aA3);  aB3 = fmaf(wB, (float)vqB[3], aB3);
        aA4 = fmaf(wA, (float)vqA[4], aA4);  aB4 = fmaf(wB, (float)vqB[4], aB4);
        aA5 = fmaf(wA, (float)vqA[5], aA5);  aB5 = fmaf(wB, (float)vqB[5], aB5);
        aA6 = fmaf(wA, (float)vqA[6], aA6);  aB6 = fmaf(wB, (float)vqB[6], aB6);
        aA7 = fmaf(wA, (float)vqA[7], aA7);  aB7 = fmaf(wB, (float)vqB[7], aB7);
    }
    float s = sA + sB, sea = seaA + seaB;
    float a0 = aA0 + aB0, a1 = aA1 + aB1, a2 = aA2 + aB2, a3 = aA3 + aB3;
    float a4 = aA4 + aB4, a5 = aA5 + aB5, a6 = aA6 + aB6, a7 = aA7 + aB7;

    // merge the two edge slots (lane ^ 32): plain sums
    s += __shfl_xor(s, 32, 64);
    sea += __shfl_xor(sea, 32, 64);
    a0 += __shfl_xor(a0, 32, 64);
    a1 += __shfl_xor(a1, 32, 64);
    a2 += __shfl_xor(a2, 32, 64);
    a3 += __shfl_xor(a3, 32, 64);
    a4 += __shfl_xor(a4, 32, 64);
    a5 += __shfl_xor(a5, 32, 64);
    a6 += __shfl_xor(a6, 32, 64);
    a7 += __shfl_xor(a7, 32, 64);

    float inv = (s > 0.f) ? 1.f / s : 1.f;
    float sw = sea * inv;
    float o0 = a0 * inv + sw * wea.x;
    float o1 = a1 * inv + sw * wea.y;
    float o2 = a2 * inv + sw * wea.z;
    float o3 = a3 * inv + sw * wea.w;
    float o4 = a4 * inv + sw * web.x;
    float o5 = a5 * inv + sw * web.y;
    float o6 = a6 * inv + sw * web.z;
    float o7 = a7 * inv + sw * web.w;
    // head mean (h <-> h^1 is lane ^ 16)
    o0 = 0.5f * (o0 + __shfl_xor(o0, 16, 64));
    o1 = 0.5f * (o1 + __shfl_xor(o1, 16, 64));
    o2 = 0.5f * (o2 + __shfl_xor(o2, 16, 64));
    o3 = 0.5f * (o3 + __shfl_xor(o3, 16, 64));
    o4 = 0.5f * (o4 + __shfl_xor(o4, 16, 64));
    o5 = 0.5f * (o5 + __shfl_xor(o5, 16, 64));
    o6 = 0.5f * (o6 + __shfl_xor(o6, 16, 64));
    o7 = 0.5f * (o7 + __shfl_xor(o7, 16, 64));

    // + skip (f16), ELU, residual, LN (dims dbase..dbase+7; 4x redundant across (slot,h))
    const _Float16* skp = (const _Float16*)skipbuf + n * 128 + dbase;
    half8v skh = *(const half8v*)skp;
    const float* xrp = xcur + n * 128 + dbase;
    float4 xra = *(const float4*)xrp, xrb = *(const float4*)(xrp + 4);
    float y0 = o0 + (float)skh[0], y1 = o1 + (float)skh[1], y2 = o2 + (float)skh[2], y3 = o3 + (float)skh[3];
    float y4 = o4 + (float)skh[4], y5 = o5 + (float)skh[5], y6 = o6 + (float)skh[6], y7 = o7 + (float)skh[7];
    y0 = (y0 > 0.f) ? y0 : __expf(y0) - 1.f;
    y1 = (y1 > 0.f) ? y1 : __expf(y1) - 1.f;
    y2 = (y2 > 0.f) ? y2 : __expf(y2) - 1.f;
    y3 = (y3 > 0.f) ? y3 : __expf(y3) - 1.f;
    y4 = (y4 > 0.f) ? y4 : __expf(y4) - 1.f;
    y5 = (y5 > 0.f) ? y5 : __expf(y5) - 1.f;
    y6 = (y6 > 0.f) ? y6 : __expf(y6) - 1.f;
    y7 = (y7 > 0.f) ? y7 : __expf(y7) - 1.f;
    float p0 = xra.x + y0, p1 = xra.y + y1, p2 = xra.z + y2, p3 = xra.w + y3;
    float p4 = xrb.x + y4, p5 = xrb.y + y5, p6 = xrb.z + y6, p7 = xrb.w + y7;
    float mu = wred16(p0 + p1 + p2 + p3 + p4 + p5 + p6 + p7) * (1.f / 128.f);
    float c0 = p0 - mu, c1 = p1 - mu, c2 = p2 - mu, c3 = p3 - mu;
    float c4 = p4 - mu, c5 = p5 - mu, c6 = p6 - mu, c7 = p7 - mu;
    float var = wred16(c0 * c0 + c1 * c1 + c2 * c2 + c3 * c3 +
                       c4 * c4 + c5 * c5 + c6 * c6 + c7 * c7) * (1.f / 128.f);
    float r = rsqrtf(var + 1e-5f);
    if (lane < 16) {
        const float* gp = g + dbase;
        const float* bp = beta + dbase;
        float4 ga = *(const float4*)gp, gb = *(const float4*)(gp + 4);
        float4 ba = *(const float4*)bp, bb = *(const float4*)(bp + 4);
        float4 oa, ob;
        oa.x = c0 * r * ga.x + ba.x; oa.y = c1 * r * ga.y + ba.y;
        oa.z = c2 * r * ga.z + ba.z; oa.w = c3 * r * ga.w + ba.w;
        ob.x = c4 * r * gb.x + bb.x; ob.y = c5 * r * gb.y + bb.y;
        ob.z = c6 * r * gb.z + bb.z; ob.w = c7 * r * gb.w + bb.w;
        float* dp = dst + n * 128 + dbase;
        *(float4*)dp = oa;
        *(float4*)(dp + 4) = ob;
        if (xbout) {
            uint4 pk;
            pk.x = (unsigned)f2bf(oa.x) | ((unsigned)f2bf(oa.y) << 16);
            pk.y = (unsigned)f2bf(oa.z) | ((unsigned)f2bf(oa.w) << 16);
            pk.z = (unsigned)f2bf(ob.x) | ((unsigned)f2bf(ob.y) << 16);
            pk.w = (unsigned)f2bf(ob.z) | ((unsigned)f2bf(ob.w) << 16);
            *(uint4*)(xbout + n * 128 + dbase) = pk;
        }
    }
}

// ---------- launch ----------
extern "C" void kernel_launch(void* const* d_in, const int* in_sizes, int n_in,
                              void* d_out, int out_size, void* d_ws, size_t ws_size,
                              hipStream_t stream) {
    const float* x       = (const float*)d_in[0];
    const int*   ei      = (const int*)d_in[1];
    const float* eattr   = (const float*)d_in[2];
    const float* ln_in_g = (const float*)d_in[3];
    const float* ln_in_b = (const float*)d_in[4];
    const float* Wq = (const float*)d_in[5];
    const float* bq = (const float*)d_in[6];
    const float* Wk = (const float*)d_in[7];
    const float* bk = (const float*)d_in[8];
    const float* Wv = (const float*)d_in[9];
    const float* bv = (const float*)d_in[10];
    const float* We = (const float*)d_in[11];
    const float* Ws = (const float*)d_in[12];
    const float* bs = (const float*)d_in[13];
    const float* ln_g = (const float*)d_in[14];
    const float* ln_b = (const float*)d_in[15];
    float* out = (float*)d_out;

    char* p = (char*)d_ws;
    auto carve = [&](size_t bytes) {
        char* r = p;
        p += (bytes + 255) & ~(size_t)255;
        return (void*)r;
    };
    int*  cnt       = (int*)carve((size_t)NN * 4);
    int*  row_state = (int*)carve((size_t)NN * 4);
    int*  bsums     = (int*)carve(1024);
    int2* csr       = (int2*)carve((size_t)NE * 8);
    unsigned short* WcatT = (unsigned short*)carve((size_t)NLAYERS * MCOLS * HIDS * 2);
    float* bcat     = (float*)carve((size_t)NLAYERS * MCOLS * 4);
    float* xcur     = (float*)carve((size_t)NN * HIDS * 4);
    unsigned short* qpack  = (unsigned short*)carve((size_t)NN * 256 * 2);
    unsigned short* kvpack = (unsigned short*)carve((size_t)NN * 512 * 2);
    unsigned short* skipbuf = (unsigned short*)carve((size_t)NN * HIDS * 2);
    unsigned short* xb = (unsigned short*)carve((size_t)NN * HIDS * 2);

    const int NB_N = (NN + 255) / 256;        // 196
    const int NB_E1K = (NE + 1023) / 1024;    // 489
    const int NODE_BLOCKS = (NN + 3) / 4;     // 12500

    // CSR build (edge_index layout: src = ei[0:E], tgt = ei[E:2E])
    hipMemsetAsync(cnt, 0, (size_t)NN * 4, stream);
    eatb_count<<<NB_E1K, 1024, 0, stream>>>(ei + NE, cnt);
    eatb_blocksum<<<NB_N, 256, 0, stream>>>(cnt, bsums);
    eatb_scanb<<<1, 256, 0, stream>>>(bsums, NB_N);
    eatb_rowstart<<<NB_N, 256, 0, stream>>>(cnt, bsums, row_state);
    eatb_scatter<<<NB_E1K, 1024, 0, stream>>>(ei, ei + NE, eattr, row_state, csr);

    // pack weights (transposed bf16) + biases
    {
        int tot = NLAYERS * MCOLS * HIDS + NLAYERS * MCOLS;
        eatb_packw<<<(tot + 255) / 256, 256, 0, stream>>>(Wq, Wk, Wv, Ws, bq, bk, bv, bs, WcatT, bcat);
    }

    // input layernorm -> xcur (fp32) + xb (bf16)
    eatb_ln_in<<<NODE_BLOCKS, 256, 0, stream>>>(x, ln_in_g, ln_in_b, xcur, xb);

    // layers
    const int GEMM_BLOCKS = (NN + 127) / 128;   // 391
    for (int l = 0; l < NLAYERS; ++l) {
        eatb_gemm<<<GEMM_BLOCKS, 512, 0, stream>>>(xb, WcatT + (size_t)l * MCOLS * HIDS,
                                                   bcat + (size_t)l * MCOLS, qpack, kvpack, skipbuf);
        float* dst = (l == NLAYERS - 1) ? out : xcur;
        unsigned short* xbo = (l == NLAYERS - 1) ? nullptr : xb;
        eatb_attn<<<NODE_BLOCKS, 256, 0, stream>>>(qpack, kvpack, skipbuf, csr, row_state,
                                                   We + (size_t)l * 256, ln_g + (size_t)l * 128,
                                                   ln_b + (size_t)l * 128, xcur, dst, xbo);
    }
    (void)in_sizes; (void)n_in; (void)out_size; (void)ws_size;
}